// Round 1
// baseline (1656.014 us; speedup 1.0000x reference)
//
#include <hip/hip_runtime.h>
#include <math.h>

#define BB 16
#define LL 1024
#define DM 6
#define ED 48
#define NST 32
#define DCONVK 16
#define NCLS 4
#define CH 64   // positions per pre-kernel block

__device__ __forceinline__ float softplus_f(float x) {
    return fmaxf(x, 0.f) + log1pf(expf(-fabsf(x)));
}
__device__ __forceinline__ float silu_f(float x) {
    return x / (1.f + expf(-x));
}

// Fused: rmsnorm -> in_proj -> split(xs,z) -> causal depthwise conv + silu -> x_proj
//        -> (dlt, Bm, Cm) -> delta = softplus(dlt*dt_w + dt_b)
__global__ __launch_bounds__(256) void pre_kernel(
    const float* __restrict__ hin,   // (B,L,6)
    const float* __restrict__ ipw,   // (6,96)
    const float* __restrict__ nw,    // (6)
    const float* __restrict__ cw,    // (48,16)
    const float* __restrict__ cb,    // (48)
    const float* __restrict__ xpw,   // (48,65)
    const float* __restrict__ dtw,   // (48)
    const float* __restrict__ dtb,   // (48)
    float* __restrict__ xs_o,        // (B,L,48)
    float* __restrict__ z_o,         // (B,L,48)
    float* __restrict__ delta_o,     // (B,L,48)
    float* __restrict__ Bm_o,        // (B,L,32)
    float* __restrict__ Cm_o)        // (B,L,32)
{
    __shared__ float s_ipw[6*96];
    __shared__ float s_nw[6];
    __shared__ float s_cw[48*DCONVK];
    __shared__ float s_cb[48];
    __shared__ float s_xpw[48*65];
    __shared__ float s_dtw[48];
    __shared__ float s_dtb[48];
    __shared__ float s_raw[(CH+15)*48];
    __shared__ float s_xs[CH*48];
    __shared__ float s_dlt[CH];

    const int tid = threadIdx.x;
    const int b  = blockIdx.x >> 4;
    const int l0 = (blockIdx.x & 15) * CH;

    for (int i = tid; i < 6*96; i += 256) s_ipw[i] = ipw[i];
    if (tid < 6) s_nw[tid] = nw[tid];
    for (int i = tid; i < 48*DCONVK; i += 256) s_cw[i] = cw[i];
    if (tid < 48) s_cb[tid] = cb[tid];
    for (int i = tid; i < 48*65; i += 256) s_xpw[i] = xpw[i];
    if (tid < 48) { s_dtw[tid] = dtw[tid]; s_dtb[tid] = dtb[tid]; }
    __syncthreads();

    // phase 1: rmsnorm + in_proj for l in [l0-15, l0+CH)
    for (int t = tid; t < CH + 15; t += 256) {
        int l = l0 - 15 + t;
        if (l < 0) {
            for (int c = 0; c < 48; ++c) s_raw[t*48+c] = 0.f;
        } else {
            float u[DM]; float ss = 0.f;
            const float* hp = hin + ((size_t)b*LL + l)*DM;
            #pragma unroll
            for (int d = 0; d < DM; ++d) { u[d] = hp[d]; ss += u[d]*u[d]; }
            float sc = 1.f / sqrtf(ss * (1.f/DM) + 1e-5f);
            #pragma unroll
            for (int d = 0; d < DM; ++d) u[d] *= sc * s_nw[d];
            float* zrow = z_o + ((size_t)b*LL + l)*48;
            for (int j = 0; j < 96; ++j) {
                float acc = 0.f;
                #pragma unroll
                for (int d = 0; d < DM; ++d) acc += u[d]*s_ipw[d*96+j];
                if (j < 48) s_raw[t*48+j] = acc;
                else if (l >= l0) zrow[j-48] = acc;
            }
        }
    }
    __syncthreads();

    // phase 2: depthwise causal conv (K=16) + silu
    for (int o = tid; o < CH*48; o += 256) {
        int p = o / 48, c = o % 48;
        float acc = s_cb[c];
        #pragma unroll
        for (int k = 0; k < DCONVK; ++k)
            acc += s_raw[(p+k)*48 + c] * s_cw[c*DCONVK + k];
        float v = silu_f(acc);
        s_xs[p*48+c] = v;
        xs_o[((size_t)b*LL + l0 + p)*48 + c] = v;
    }
    __syncthreads();

    // phase 3: x_proj -> dlt (col 0), Bm (cols 1..32), Cm (cols 33..64)
    if (tid < CH) {
        float acc = 0.f;
        for (int e = 0; e < 48; ++e) acc += s_xs[tid*48+e]*s_xpw[e*65];
        s_dlt[tid] = acc;
    }
    for (int o = tid; o < CH*64; o += 256) {
        int p = o >> 6, j = o & 63;
        float acc = 0.f;
        for (int e = 0; e < 48; ++e) acc += s_xs[p*48+e]*s_xpw[e*65 + 1 + j];
        size_t base = ((size_t)b*LL + l0 + p)*32;
        if (j < 32) Bm_o[base + j] = acc;
        else        Cm_o[base + (j-32)] = acc;
    }
    __syncthreads();

    // phase 4: delta = softplus(dlt*dt_w + dt_b)
    for (int o = tid; o < CH*48; o += 256) {
        int p = o / 48, e = o % 48;
        float xv = s_dlt[p]*s_dtw[e] + s_dtb[e];
        delta_o[((size_t)b*LL + l0 + p)*48 + e] = softplus_f(xv);
    }
}

// Sequential selective scan. One wave per (b, 2 channels e). lane = (e&1)*32 + n.
// Fuses + D*xs and *silu(z) into the output write.
__global__ __launch_bounds__(64) void scan_kernel(
    const float* __restrict__ xs,
    const float* __restrict__ z,
    const float* __restrict__ delta,
    const float* __restrict__ Bm,
    const float* __restrict__ Cm,
    const float* __restrict__ A_log,  // (48,32)
    const float* __restrict__ Dw,     // (48)
    float* __restrict__ yg)           // (B,L,48) gated output
{
    const int tid = threadIdx.x;
    const int b = blockIdx.x / 24;
    const int e = (blockIdx.x % 24)*2 + (tid >> 5);
    const int n = tid & 31;

    const float Ac = -expf(A_log[e*NST + n]);
    const float Dc = Dw[e];
    float h = 0.f;

    const float* dp = delta + ((size_t)b*LL)*48 + e;
    const float* xp = xs    + ((size_t)b*LL)*48 + e;
    const float* zp = z     + ((size_t)b*LL)*48 + e;
    const float* bp = Bm + ((size_t)b*LL)*32 + n;
    const float* cp = Cm + ((size_t)b*LL)*32 + n;
    float*       yp = yg + ((size_t)b*LL)*48 + e;

    for (int l = 0; l < LL; ++l) {
        float dv = dp[(size_t)l*48];
        float xv = xp[(size_t)l*48];
        float bm = bp[(size_t)l*32];
        float cm = cp[(size_t)l*32];
        float dA  = expf(dv * Ac);
        float dBx = dv * xv * bm;
        h = fmaf(dA, h, dBx);
        float part = h * cm;
        part += __shfl_xor(part, 16);
        part += __shfl_xor(part, 8);
        part += __shfl_xor(part, 4);
        part += __shfl_xor(part, 2);
        part += __shfl_xor(part, 1);
        if (n == 0) {
            float yfull = part + Dc * xv;
            float zv = zp[(size_t)l*48];
            yp[(size_t)l*48] = yfull * silu_f(zv);
        }
    }
}

// h1 = yg @ out_proj_w (48->6) + x   (residual)
__global__ __launch_bounds__(256) void proj0_kernel(
    const float* __restrict__ yg,
    const float* __restrict__ x,
    const float* __restrict__ opw,   // (48,6)
    float* __restrict__ h1)
{
    __shared__ float s_w[48*6];
    const int tid = threadIdx.x;
    for (int i = tid; i < 48*6; i += 256) s_w[i] = opw[i];
    __syncthreads();
    const int idx = blockIdx.x*256 + tid;     // (b*L + l), grid covers exactly B*L
    const float* yr = yg + (size_t)idx*48;
    float acc[DM] = {0,0,0,0,0,0};
    for (int e = 0; e < 48; ++e) {
        float v = yr[e];
        #pragma unroll
        for (int d = 0; d < DM; ++d) acc[d] += v * s_w[e*DM+d];
    }
    const float* xr = x + (size_t)idx*DM;
    float* hr = h1 + (size_t)idx*DM;
    #pragma unroll
    for (int d = 0; d < DM; ++d) hr[d] = acc[d] + xr[d];
}

// feat = relu(h_last @ fc_w + fc_b); logits = feat@cls_w+cls_b; mass = feat@reg_w+reg_b
__global__ __launch_bounds__(1024) void head_kernel(
    const float* __restrict__ yg,    // layer-1 gated output (B,L,48)
    const float* __restrict__ fcw, const float* __restrict__ fcb,
    const float* __restrict__ clw, const float* __restrict__ clb,
    const float* __restrict__ rgw, const float* __restrict__ rgb,
    float* __restrict__ out)         // 80 floats: (16,4) logits then (16,) mass
{
    __shared__ float s_h[BB*48];
    __shared__ float s_f[BB*48];
    const int tid = threadIdx.x;
    const int b = tid >> 6, j = tid & 63;
    if (j < 48) s_h[b*48+j] = yg[((size_t)b*LL + (LL-1))*48 + j];
    __syncthreads();
    if (j < 48) {
        float acc = fcb[j];
        for (int k = 0; k < 48; ++k) acc += s_h[b*48+k]*fcw[k*48+j];
        s_f[b*48+j] = fmaxf(acc, 0.f);
    }
    __syncthreads();
    if (j < NCLS) {
        float acc = clb[j];
        for (int k = 0; k < 48; ++k) acc += s_f[b*48+k]*clw[k*NCLS+j];
        out[b*NCLS + j] = acc;
    }
    if (j == NCLS) {
        float acc = rgb[0];
        for (int k = 0; k < 48; ++k) acc += s_f[b*48+k]*rgw[k];
        out[BB*NCLS + b] = acc;
    }
}

extern "C" void kernel_launch(void* const* d_in, const int* in_sizes, int n_in,
                              void* d_out, int out_size, void* d_ws, size_t ws_size,
                              hipStream_t stream)
{
    const float* x     = (const float*)d_in[0];
    const float* ipw   = (const float*)d_in[1];   // (2,6,96)
    const float* cw    = (const float*)d_in[2];   // (2,48,16)
    const float* cb    = (const float*)d_in[3];   // (2,48)
    const float* xpw   = (const float*)d_in[4];   // (2,48,65)
    const float* dtw   = (const float*)d_in[5];   // (2,1,48)
    const float* dtb   = (const float*)d_in[6];   // (2,48)
    const float* A_log = (const float*)d_in[7];   // (2,48,32)
    const float* Dw    = (const float*)d_in[8];   // (2,48)
    const float* nw    = (const float*)d_in[9];   // (2,6)
    const float* opw   = (const float*)d_in[10];  // (1,48,6)
    const float* fcw   = (const float*)d_in[11];
    const float* fcb   = (const float*)d_in[12];
    const float* clw   = (const float*)d_in[13];
    const float* clb   = (const float*)d_in[14];
    const float* rgw   = (const float*)d_in[15];
    const float* rgb   = (const float*)d_in[16];
    float* out = (float*)d_out;

    float* ws = (float*)d_ws;
    const size_t BL = (size_t)BB*LL;
    float* xs    = ws;
    float* z     = xs    + BL*48;
    float* delta = z     + BL*48;
    float* Bmw   = delta + BL*48;
    float* Cmw   = Bmw   + BL*32;
    float* yg    = Cmw   + BL*32;
    float* h1    = yg    + BL*48;

    // ---- layer 0 ----
    pre_kernel<<<dim3(BB*16), dim3(256), 0, stream>>>(
        x, ipw, nw, cw, cb, xpw, dtw, dtb, xs, z, delta, Bmw, Cmw);
    scan_kernel<<<dim3(BB*24), dim3(64), 0, stream>>>(
        xs, z, delta, Bmw, Cmw, A_log, Dw, yg);
    proj0_kernel<<<dim3(BB*LL/256), dim3(256), 0, stream>>>(yg, x, opw, h1);

    // ---- layer 1 ----
    pre_kernel<<<dim3(BB*16), dim3(256), 0, stream>>>(
        h1, ipw + 6*96, nw + 6, cw + 48*DCONVK, cb + 48,
        xpw + 48*65, dtw + 48, dtb + 48, xs, z, delta, Bmw, Cmw);
    scan_kernel<<<dim3(BB*24), dim3(64), 0, stream>>>(
        xs, z, delta, Bmw, Cmw, A_log + 48*NST, Dw + 48, yg);

    head_kernel<<<dim3(1), dim3(1024), 0, stream>>>(
        yg, fcw, fcb, clw, clb, rgw, rgb, out);
}

// Round 2
// 294.159 us; speedup vs baseline: 5.6297x; 5.6297x over previous
//
#include <hip/hip_runtime.h>
#include <math.h>

#define BB 16
#define LL 1024
#define DM 6
#define ED 48
#define NST 32
#define DCONVK 16
#define NCLS 4
#define CH 64   // positions per pre-kernel block
#define NC 32   // scan chunks
#define CS 32   // chunk size = LL/NC

__device__ __forceinline__ float softplus_f(float x) {
    return fmaxf(x, 0.f) + log1pf(expf(-fabsf(x)));
}
__device__ __forceinline__ float silu_f(float x) {
    return x / (1.f + expf(-x));
}

// Fused: rmsnorm -> in_proj -> split(xs,z) -> causal depthwise conv + silu -> x_proj
//        -> (dlt, Bm, Cm) -> delta = softplus(dlt*dt_w + dt_b)
__global__ __launch_bounds__(256) void pre_kernel(
    const float* __restrict__ hin,   // (B,L,6)
    const float* __restrict__ ipw,   // (6,96)
    const float* __restrict__ nw,    // (6)
    const float* __restrict__ cw,    // (48,16)
    const float* __restrict__ cb,    // (48)
    const float* __restrict__ xpw,   // (48,65)
    const float* __restrict__ dtw,   // (48)
    const float* __restrict__ dtb,   // (48)
    float* __restrict__ xs_o,        // (B,L,48)
    float* __restrict__ z_o,         // (B,L,48)
    float* __restrict__ delta_o,     // (B,L,48)
    float* __restrict__ Bm_o,        // (B,L,32)
    float* __restrict__ Cm_o)        // (B,L,32)
{
    __shared__ float s_ipw[6*96];
    __shared__ float s_nw[6];
    __shared__ float s_cw[48*DCONVK];
    __shared__ float s_cb[48];
    __shared__ float s_xpw[48*65];
    __shared__ float s_dtw[48];
    __shared__ float s_dtb[48];
    __shared__ float s_raw[(CH+15)*48];
    __shared__ float s_xs[CH*48];
    __shared__ float s_dlt[CH];

    const int tid = threadIdx.x;
    const int b  = blockIdx.x >> 4;
    const int l0 = (blockIdx.x & 15) * CH;

    for (int i = tid; i < 6*96; i += 256) s_ipw[i] = ipw[i];
    if (tid < 6) s_nw[tid] = nw[tid];
    for (int i = tid; i < 48*DCONVK; i += 256) s_cw[i] = cw[i];
    if (tid < 48) s_cb[tid] = cb[tid];
    for (int i = tid; i < 48*65; i += 256) s_xpw[i] = xpw[i];
    if (tid < 48) { s_dtw[tid] = dtw[tid]; s_dtb[tid] = dtb[tid]; }
    __syncthreads();

    // phase 1: rmsnorm + in_proj for l in [l0-15, l0+CH)
    for (int t = tid; t < CH + 15; t += 256) {
        int l = l0 - 15 + t;
        if (l < 0) {
            for (int c = 0; c < 48; ++c) s_raw[t*48+c] = 0.f;
        } else {
            float u[DM]; float ss = 0.f;
            const float* hp = hin + ((size_t)b*LL + l)*DM;
            #pragma unroll
            for (int d = 0; d < DM; ++d) { u[d] = hp[d]; ss += u[d]*u[d]; }
            float sc = 1.f / sqrtf(ss * (1.f/DM) + 1e-5f);
            #pragma unroll
            for (int d = 0; d < DM; ++d) u[d] *= sc * s_nw[d];
            float* zrow = z_o + ((size_t)b*LL + l)*48;
            for (int j = 0; j < 96; ++j) {
                float acc = 0.f;
                #pragma unroll
                for (int d = 0; d < DM; ++d) acc += u[d]*s_ipw[d*96+j];
                if (j < 48) s_raw[t*48+j] = acc;
                else if (l >= l0) zrow[j-48] = acc;
            }
        }
    }
    __syncthreads();

    // phase 2: depthwise causal conv (K=16) + silu
    for (int o = tid; o < CH*48; o += 256) {
        int p = o / 48, c = o % 48;
        float acc = s_cb[c];
        #pragma unroll
        for (int k = 0; k < DCONVK; ++k)
            acc += s_raw[(p+k)*48 + c] * s_cw[c*DCONVK + k];
        float v = silu_f(acc);
        s_xs[p*48+c] = v;
        xs_o[((size_t)b*LL + l0 + p)*48 + c] = v;
    }
    __syncthreads();

    // phase 3: x_proj -> dlt (col 0), Bm (cols 1..32), Cm (cols 33..64)
    if (tid < CH) {
        float acc = 0.f;
        for (int e = 0; e < 48; ++e) acc += s_xs[tid*48+e]*s_xpw[e*65];
        s_dlt[tid] = acc;
    }
    for (int o = tid; o < CH*64; o += 256) {
        int p = o >> 6, j = o & 63;
        float acc = 0.f;
        for (int e = 0; e < 48; ++e) acc += s_xs[p*48+e]*s_xpw[e*65 + 1 + j];
        size_t base = ((size_t)b*LL + l0 + p)*32;
        if (j < 32) Bm_o[base + j] = acc;
        else        Cm_o[base + (j-32)] = acc;
    }
    __syncthreads();

    // phase 4: delta = softplus(dlt*dt_w + dt_b)
    for (int o = tid; o < CH*48; o += 256) {
        int p = o / 48, e = o % 48;
        float xv = s_dlt[p]*s_dtw[e] + s_dtb[e];
        delta_o[((size_t)b*LL + l0 + p)*48 + e] = softplus_f(xv);
    }
}

// ---- chunk-parallel selective scan ----
// Lane layout: wave of 64 = 2 e-channels x 32 n-states.

// phase 1: per (b,e,chunk): local scan (h0=0) -> h_end, and P = prod(dA)
__global__ __launch_bounds__(64) void scan1_kernel(
    const float* __restrict__ delta,
    const float* __restrict__ xs,
    const float* __restrict__ Bm,
    const float* __restrict__ A_log,  // (48,32)
    float* __restrict__ Pprod,        // (B,48,NC,32)
    float* __restrict__ Hend)         // (B,48,NC,32)
{
    const int tid = threadIdx.x;
    const int c = blockIdx.x % NC;
    const int epair = (blockIdx.x / NC) % 24;
    const int b = blockIdx.x / (NC*24);
    const int e = epair*2 + (tid >> 5);
    const int n = tid & 31;

    const float Ac = -expf(A_log[e*NST + n]);
    const size_t base = (size_t)b*LL + (size_t)c*CS;
    const float* dp = delta + base*48 + e;
    const float* xp = xs    + base*48 + e;
    const float* bp = Bm    + base*32 + n;

    float h = 0.f, P = 1.f;
    #pragma unroll 4
    for (int l = 0; l < CS; ++l) {
        float dv = dp[l*48];
        float xv = xp[l*48];
        float bm = bp[l*32];
        float dA  = expf(dv * Ac);
        float dBx = dv * xv * bm;
        h = fmaf(dA, h, dBx);
        P *= dA;
    }
    const size_t o = (((size_t)b*48 + e)*NC + c)*32 + n;
    Pprod[o] = P;
    Hend[o]  = h;
}

// phase 2: carry scan over chunks per (b,e,n): Carry[c] = H_{c-1}, H_c = P_c*H_{c-1}+Hend_c
__global__ __launch_bounds__(64) void scan2_kernel(
    const float* __restrict__ Pprod,
    const float* __restrict__ Hend,
    float* __restrict__ Carry)
{
    const int tid = threadIdx.x;
    const int b = blockIdx.x / 24;
    const int e = (blockIdx.x % 24)*2 + (tid >> 5);
    const int n = tid & 31;
    const size_t base = ((size_t)b*48 + e)*NC*32 + n;
    float H = 0.f;
    for (int c = 0; c < NC; ++c) {
        Carry[base + (size_t)c*32] = H;
        H = fmaf(Pprod[base + (size_t)c*32], H, Hend[base + (size_t)c*32]);
    }
}

// phase 3: re-run recurrence seeded with carry; fuse y = sum_n h*C + D*xs, gate silu(z)
__global__ __launch_bounds__(64) void scan3_kernel(
    const float* __restrict__ xs,
    const float* __restrict__ z,
    const float* __restrict__ delta,
    const float* __restrict__ Bm,
    const float* __restrict__ Cm,
    const float* __restrict__ A_log,
    const float* __restrict__ Dw,
    const float* __restrict__ Carry,
    float* __restrict__ yg)
{
    const int tid = threadIdx.x;
    const int c = blockIdx.x % NC;
    const int epair = (blockIdx.x / NC) % 24;
    const int b = blockIdx.x / (NC*24);
    const int e = epair*2 + (tid >> 5);
    const int n = tid & 31;

    const float Ac = -expf(A_log[e*NST + n]);
    const float Dc = Dw[e];
    const size_t base = (size_t)b*LL + (size_t)c*CS;
    const float* dp = delta + base*48 + e;
    const float* xp = xs    + base*48 + e;
    const float* zp = z     + base*48 + e;
    const float* bp = Bm    + base*32 + n;
    const float* cp = Cm    + base*32 + n;
    float*       yp = yg    + base*48 + e;

    float h = Carry[(((size_t)b*48 + e)*NC + c)*32 + n];

    for (int l = 0; l < CS; ++l) {
        float dv = dp[l*48];
        float xv = xp[l*48];
        float bm = bp[l*32];
        float cm = cp[l*32];
        float dA  = expf(dv * Ac);
        float dBx = dv * xv * bm;
        h = fmaf(dA, h, dBx);
        float part = h * cm;
        part += __shfl_xor(part, 16);
        part += __shfl_xor(part, 8);
        part += __shfl_xor(part, 4);
        part += __shfl_xor(part, 2);
        part += __shfl_xor(part, 1);
        if (n == 0) {
            float yfull = part + Dc * xv;
            float zv = zp[l*48];
            yp[l*48] = yfull * silu_f(zv);
        }
    }
}

// h1 = yg @ out_proj_w (48->6) + x   (residual)
__global__ __launch_bounds__(256) void proj0_kernel(
    const float* __restrict__ yg,
    const float* __restrict__ x,
    const float* __restrict__ opw,   // (48,6)
    float* __restrict__ h1)
{
    __shared__ float s_w[48*6];
    const int tid = threadIdx.x;
    for (int i = tid; i < 48*6; i += 256) s_w[i] = opw[i];
    __syncthreads();
    const int idx = blockIdx.x*256 + tid;     // (b*L + l), grid covers exactly B*L
    const float* yr = yg + (size_t)idx*48;
    float acc[DM] = {0,0,0,0,0,0};
    for (int e = 0; e < 48; ++e) {
        float v = yr[e];
        #pragma unroll
        for (int d = 0; d < DM; ++d) acc[d] += v * s_w[e*DM+d];
    }
    const float* xr = x + (size_t)idx*DM;
    float* hr = h1 + (size_t)idx*DM;
    #pragma unroll
    for (int d = 0; d < DM; ++d) hr[d] = acc[d] + xr[d];
}

// feat = relu(h_last @ fc_w + fc_b); logits = feat@cls_w+cls_b; mass = feat@reg_w+reg_b
__global__ __launch_bounds__(1024) void head_kernel(
    const float* __restrict__ yg,    // layer-1 gated output (B,L,48)
    const float* __restrict__ fcw, const float* __restrict__ fcb,
    const float* __restrict__ clw, const float* __restrict__ clb,
    const float* __restrict__ rgw, const float* __restrict__ rgb,
    float* __restrict__ out)         // 80 floats: (16,4) logits then (16,) mass
{
    __shared__ float s_h[BB*48];
    __shared__ float s_f[BB*48];
    const int tid = threadIdx.x;
    const int b = tid >> 6, j = tid & 63;
    if (j < 48) s_h[b*48+j] = yg[((size_t)b*LL + (LL-1))*48 + j];
    __syncthreads();
    if (j < 48) {
        float acc = fcb[j];
        for (int k = 0; k < 48; ++k) acc += s_h[b*48+k]*fcw[k*48+j];
        s_f[b*48+j] = fmaxf(acc, 0.f);
    }
    __syncthreads();
    if (j < NCLS) {
        float acc = clb[j];
        for (int k = 0; k < 48; ++k) acc += s_f[b*48+k]*clw[k*NCLS+j];
        out[b*NCLS + j] = acc;
    }
    if (j == NCLS) {
        float acc = rgb[0];
        for (int k = 0; k < 48; ++k) acc += s_f[b*48+k]*rgw[k];
        out[BB*NCLS + b] = acc;
    }
}

extern "C" void kernel_launch(void* const* d_in, const int* in_sizes, int n_in,
                              void* d_out, int out_size, void* d_ws, size_t ws_size,
                              hipStream_t stream)
{
    const float* x     = (const float*)d_in[0];
    const float* ipw   = (const float*)d_in[1];   // (2,6,96)
    const float* cw    = (const float*)d_in[2];   // (2,48,16)
    const float* cb    = (const float*)d_in[3];   // (2,48)
    const float* xpw   = (const float*)d_in[4];   // (2,48,65)
    const float* dtw   = (const float*)d_in[5];   // (2,1,48)
    const float* dtb   = (const float*)d_in[6];   // (2,48)
    const float* A_log = (const float*)d_in[7];   // (2,48,32)
    const float* Dw    = (const float*)d_in[8];   // (2,48)
    const float* nw    = (const float*)d_in[9];   // (2,6)
    const float* opw   = (const float*)d_in[10];  // (1,48,6)
    const float* fcw   = (const float*)d_in[11];
    const float* fcb   = (const float*)d_in[12];
    const float* clw   = (const float*)d_in[13];
    const float* clb   = (const float*)d_in[14];
    const float* rgw   = (const float*)d_in[15];
    const float* rgb   = (const float*)d_in[16];
    float* out = (float*)d_out;

    float* ws = (float*)d_ws;
    const size_t BL = (size_t)BB*LL;
    const size_t SC = (size_t)BB*48*NC*32;  // scan scratch per array
    float* xs    = ws;
    float* z     = xs    + BL*48;
    float* delta = z     + BL*48;
    float* Bmw   = delta + BL*48;
    float* Cmw   = Bmw   + BL*32;
    float* yg    = Cmw   + BL*32;
    float* h1    = yg    + BL*48;
    float* Pp    = h1    + BL*8;
    float* He    = Pp    + SC;
    float* Ca    = He    + SC;

    const dim3 scanGrid(BB*24*NC), scanBlk(64);

    // ---- layer 0 ----
    pre_kernel<<<dim3(BB*16), dim3(256), 0, stream>>>(
        x, ipw, nw, cw, cb, xpw, dtw, dtb, xs, z, delta, Bmw, Cmw);
    scan1_kernel<<<scanGrid, scanBlk, 0, stream>>>(delta, xs, Bmw, A_log, Pp, He);
    scan2_kernel<<<dim3(BB*24), scanBlk, 0, stream>>>(Pp, He, Ca);
    scan3_kernel<<<scanGrid, scanBlk, 0, stream>>>(
        xs, z, delta, Bmw, Cmw, A_log, Dw, Ca, yg);
    proj0_kernel<<<dim3(BB*LL/256), dim3(256), 0, stream>>>(yg, x, opw, h1);

    // ---- layer 1 ----
    pre_kernel<<<dim3(BB*16), dim3(256), 0, stream>>>(
        h1, ipw + 6*96, nw + 6, cw + 48*DCONVK, cb + 48,
        xpw + 48*65, dtw + 48, dtb + 48, xs, z, delta, Bmw, Cmw);
    scan1_kernel<<<scanGrid, scanBlk, 0, stream>>>(
        delta, xs, Bmw, A_log + 48*NST, Pp, He);
    scan2_kernel<<<dim3(BB*24), scanBlk, 0, stream>>>(Pp, He, Ca);
    scan3_kernel<<<scanGrid, scanBlk, 0, stream>>>(
        xs, z, delta, Bmw, Cmw, A_log + 48*NST, Dw + 48, Ca, yg);

    head_kernel<<<dim3(1), dim3(1024), 0, stream>>>(
        yg, fcw, fcb, clw, clb, rgw, rgb, out);
}

// Round 3
// 277.062 us; speedup vs baseline: 5.9770x; 1.0617x over previous
//
#include <hip/hip_runtime.h>
#include <math.h>

#define BB 16
#define LL 1024
#define DM 6
#define ED 48
#define NST 32
#define DCONVK 16
#define NCLS 4
#define CH 64   // positions per pre-kernel block
#define NC 32   // scan chunks
#define CS 32   // chunk size = LL/NC

__device__ __forceinline__ float softplus_f(float x) {
    return fmaxf(x, 0.f) + log1pf(expf(-fabsf(x)));
}
__device__ __forceinline__ float silu_f(float x) {
    return x / (1.f + __expf(-x));
}

// Fused: rmsnorm -> in_proj -> split(xs,z) -> causal depthwise conv + silu -> x_proj
//        -> (dlt, Bm, Cm) -> delta = softplus(dlt*dt_w + dt_b)
// All big outputs written TRANSPOSED: xT/zT/dT = (B,48,L), BT/CT = (B,32,L)
__global__ __launch_bounds__(256) void pre_kernel(
    const float* __restrict__ hin,   // (B,L,6)
    const float* __restrict__ ipw,   // (6,96)
    const float* __restrict__ nw,    // (6)
    const float* __restrict__ cw,    // (48,16)
    const float* __restrict__ cb,    // (48)
    const float* __restrict__ xpw,   // (48,65)
    const float* __restrict__ dtw,   // (48)
    const float* __restrict__ dtb,   // (48)
    float* __restrict__ xT,          // (B,48,L)
    float* __restrict__ zT,          // (B,48,L)
    float* __restrict__ dT,          // (B,48,L)
    float* __restrict__ BT,          // (B,32,L)
    float* __restrict__ CT)          // (B,32,L)
{
    __shared__ float s_ipw[6*96];
    __shared__ float s_nw[6];
    __shared__ float s_cw[48*DCONVK];
    __shared__ float s_cb[48];
    __shared__ float s_xpw[48*65];
    __shared__ float s_dtw[48];
    __shared__ float s_dtb[48];
    __shared__ float s_u[(CH+15)*7];     // rmsnormed input (pad 7)
    __shared__ float s_raw[(CH+15)*49];  // conv input (pad 49)
    __shared__ float s_xs[CH*49];        // conv output (pad 49)
    __shared__ float s_dlt[CH];

    const int tid = threadIdx.x;
    const int b  = blockIdx.x >> 4;
    const int l0 = (blockIdx.x & 15) * CH;

    for (int i = tid; i < 6*96; i += 256) s_ipw[i] = ipw[i];
    if (tid < 6) s_nw[tid] = nw[tid];
    for (int i = tid; i < 48*DCONVK; i += 256) s_cw[i] = cw[i];
    if (tid < 48) s_cb[tid] = cb[tid];
    for (int i = tid; i < 48*65; i += 256) s_xpw[i] = xpw[i];
    if (tid < 48) { s_dtw[tid] = dtw[tid]; s_dtb[tid] = dtb[tid]; }
    __syncthreads();

    // phase 0: rmsnorm -> s_u  (CH+15 rows)
    if (tid < CH + 15) {
        int l = l0 - 15 + tid;
        float u[DM];
        if (l >= 0) {
            float ss = 0.f;
            const float* hp = hin + ((size_t)b*LL + l)*DM;
            #pragma unroll
            for (int d = 0; d < DM; ++d) { u[d] = hp[d]; ss += u[d]*u[d]; }
            float sc = rsqrtf(ss * (1.f/DM) + 1e-5f);
            #pragma unroll
            for (int d = 0; d < DM; ++d) u[d] *= sc * s_nw[d];
        } else {
            #pragma unroll
            for (int d = 0; d < DM; ++d) u[d] = 0.f;
        }
        #pragma unroll
        for (int d = 0; d < DM; ++d) s_u[tid*7+d] = u[d];
    }
    __syncthreads();

    // phase 1: in_proj. items i = j*80 + t; j in [0,96), t in [0,80)
    for (int i = tid; i < 96*80; i += 256) {
        int j = i / 80, t = i - j*80;
        if (t < CH + 15) {
            float acc = 0.f;
            #pragma unroll
            for (int d = 0; d < DM; ++d) acc += s_u[t*7+d]*s_ipw[d*96+j];
            if (j < 48) s_raw[t*49+j] = acc;
            else if (t >= 15) zT[((size_t)b*48 + (j-48))*LL + (l0-15+t)] = acc;
        }
    }
    __syncthreads();

    // phase 2: depthwise causal conv (K=16) + silu. o = c*64 + p (p fastest)
    for (int o = tid; o < 48*CH; o += 256) {
        int c = o >> 6, p = o & 63;
        float acc = s_cb[c];
        #pragma unroll
        for (int k = 0; k < DCONVK; ++k)
            acc += s_raw[(p+k)*49 + c] * s_cw[c*DCONVK + k];
        float v = silu_f(acc);
        s_xs[p*49+c] = v;
        xT[((size_t)b*48+c)*LL + l0 + p] = v;
    }
    __syncthreads();

    // phase 3: x_proj. o = j*64 + p; j in [0,65): j<32 -> B col j, j<64 -> C col j-32, j==64 -> dlt
    for (int o = tid; o < 65*CH; o += 256) {
        int j = o >> 6, p = o & 63;
        int col = (j == 64) ? 0 : (j + 1);
        float acc = 0.f;
        for (int e = 0; e < 48; ++e) acc += s_xs[p*49+e]*s_xpw[e*65 + col];
        int l = l0 + p;
        if (j < 32)      BT[((size_t)b*32 + j)*LL + l] = acc;
        else if (j < 64) CT[((size_t)b*32 + (j-32))*LL + l] = acc;
        else             s_dlt[p] = acc;
    }
    __syncthreads();

    // phase 4: delta = softplus(dlt*dt_w + dt_b). o = e*64 + p
    for (int o = tid; o < 48*CH; o += 256) {
        int e = o >> 6, p = o & 63;
        float xv = s_dlt[p]*s_dtw[e] + s_dtb[e];
        dT[((size_t)b*48+e)*LL + l0 + p] = softplus_f(xv);
    }
}

// ---- chunk-parallel selective scan ----
// Wave of 64 = 2 e-channels x 32 n-states. Carry arrays laid out (B,48,NC,32).

__global__ __launch_bounds__(64) void scan1_kernel(
    const float* __restrict__ dT,
    const float* __restrict__ xT,
    const float* __restrict__ BT,
    const float* __restrict__ A_log,  // (48,32)
    float* __restrict__ Pp,           // (B,48,NC,32)
    float* __restrict__ He)           // (B,48,NC,32)
{
    const int tid = threadIdx.x;
    const int c = blockIdx.x % NC;
    const int epair = (blockIdx.x / NC) % 24;
    const int b = blockIdx.x / (NC*24);
    const int e = epair*2 + (tid >> 5);
    const int n = tid & 31;

    const float Ac = -__expf(A_log[e*NST + n]);
    const size_t eb = ((size_t)b*48 + e)*LL + c*CS;
    const float4* dp = (const float4*)(dT + eb);
    const float4* xp = (const float4*)(xT + eb);
    const float4* bp = (const float4*)(BT + ((size_t)b*32 + n)*LL + c*CS);

    float h = 0.f, S = 0.f;
    #pragma unroll
    for (int q = 0; q < CS/4; ++q) {
        float4 d4 = dp[q], x4 = xp[q], b4 = bp[q];
        S += d4.x + d4.y + d4.z + d4.w;
        h = fmaf(__expf(d4.x*Ac), h, d4.x*x4.x*b4.x);
        h = fmaf(__expf(d4.y*Ac), h, d4.y*x4.y*b4.y);
        h = fmaf(__expf(d4.z*Ac), h, d4.z*x4.z*b4.z);
        h = fmaf(__expf(d4.w*Ac), h, d4.w*x4.w*b4.w);
    }
    const size_t o = (((size_t)b*48 + e)*NC + c)*32 + n;
    Pp[o] = __expf(Ac * S);
    He[o] = h;
}

__global__ __launch_bounds__(64) void scan2_kernel(
    const float* __restrict__ Pp,
    const float* __restrict__ He,
    float* __restrict__ Ca)
{
    const int tid = threadIdx.x;
    const int b = blockIdx.x / 24;
    const int e = (blockIdx.x % 24)*2 + (tid >> 5);
    const int n = tid & 31;
    const size_t base = ((size_t)b*48 + e)*NC*32 + n;
    // preload everything (independent loads, all in flight)
    float P[NC], H[NC];
    #pragma unroll
    for (int c = 0; c < NC; ++c) {
        P[c] = Pp[base + (size_t)c*32];
        H[c] = He[base + (size_t)c*32];
    }
    float acc = 0.f;
    #pragma unroll
    for (int c = 0; c < NC; ++c) {
        Ca[base + (size_t)c*32] = acc;
        acc = fmaf(P[c], acc, H[c]);
    }
}

__global__ __launch_bounds__(64) void scan3_kernel(
    const float* __restrict__ xT,
    const float* __restrict__ zT,
    const float* __restrict__ dT,
    const float* __restrict__ BT,
    const float* __restrict__ CT,
    const float* __restrict__ A_log,
    const float* __restrict__ Dw,
    const float* __restrict__ Ca,
    float* __restrict__ ygT)          // (B,48,L)
{
    const int tid = threadIdx.x;
    const int c = blockIdx.x % NC;
    const int epair = (blockIdx.x / NC) % 24;
    const int b = blockIdx.x / (NC*24);
    const int e = epair*2 + (tid >> 5);
    const int n = tid & 31;

    const float Ac = -__expf(A_log[e*NST + n]);
    const float Dc = Dw[e];
    const size_t eb = ((size_t)b*48 + e)*LL + c*CS;
    const float4* dp = (const float4*)(dT + eb);
    const float4* xp = (const float4*)(xT + eb);
    const float4* zp = (const float4*)(zT + eb);
    const float4* bp = (const float4*)(BT + ((size_t)b*32 + n)*LL + c*CS);
    const float4* cp = (const float4*)(CT + ((size_t)b*32 + n)*LL + c*CS);
    float4* yp = (float4*)(ygT + eb);

    float h = Ca[(((size_t)b*48 + e)*NC + c)*32 + n];

    #pragma unroll
    for (int q = 0; q < CS/4; ++q) {
        float4 d4 = dp[q], x4 = xp[q], b4 = bp[q], c4 = cp[q];
        float p0, p1, p2, p3;
        h = fmaf(__expf(d4.x*Ac), h, d4.x*x4.x*b4.x); p0 = h*c4.x;
        h = fmaf(__expf(d4.y*Ac), h, d4.y*x4.y*b4.y); p1 = h*c4.y;
        h = fmaf(__expf(d4.z*Ac), h, d4.z*x4.z*b4.z); p2 = h*c4.z;
        h = fmaf(__expf(d4.w*Ac), h, d4.w*x4.w*b4.w); p3 = h*c4.w;
        // packed butterfly: reduce 4 values over 32 lanes
        float q0 = p0 + __shfl_xor(p0, 16);
        float q1 = p1 + __shfl_xor(p1, 16);
        float q2 = p2 + __shfl_xor(p2, 16);
        float q3 = p3 + __shfl_xor(p3, 16);
        float m01 = (n & 16) ? q1 : q0;
        float m23 = (n & 16) ? q3 : q2;
        m01 += __shfl_xor(m01, 8); m23 += __shfl_xor(m23, 8);
        m01 += __shfl_xor(m01, 4); m23 += __shfl_xor(m23, 4);
        m01 += __shfl_xor(m01, 2); m23 += __shfl_xor(m23, 2);
        m01 += __shfl_xor(m01, 1); m23 += __shfl_xor(m23, 1);
        float y1 = __shfl_xor(m01, 16);   // sum(p1) into n<16 lanes
        float y3 = __shfl_xor(m23, 16);   // sum(p3)
        if (n == 0) {
            float4 z4 = zp[q];
            float4 y;
            y.x = (m01 + Dc*x4.x) * silu_f(z4.x);
            y.y = (y1  + Dc*x4.y) * silu_f(z4.y);
            y.z = (m23 + Dc*x4.z) * silu_f(z4.z);
            y.w = (y3  + Dc*x4.w) * silu_f(z4.w);
            yp[q] = y;
        }
    }
}

// h1 = ygT^T @ out_proj_w (48->6) + x   (residual). ygT is (B,48,L).
__global__ __launch_bounds__(256) void proj0_kernel(
    const float* __restrict__ ygT,
    const float* __restrict__ x,
    const float* __restrict__ opw,   // (48,6)
    float* __restrict__ h1)          // (B,L,6)
{
    __shared__ float s_w[48*6];
    const int tid = threadIdx.x;
    for (int i = tid; i < 48*6; i += 256) s_w[i] = opw[i];
    __syncthreads();
    const int idx = blockIdx.x*256 + tid;     // b*L + l
    const int b = idx >> 10;
    const int l = idx & (LL-1);
    float acc[DM] = {0,0,0,0,0,0};
    for (int e = 0; e < 48; ++e) {
        float v = ygT[((size_t)b*48 + e)*LL + l];
        #pragma unroll
        for (int d = 0; d < DM; ++d) acc[d] += v * s_w[e*DM+d];
    }
    const float* xr = x + (size_t)idx*DM;
    float* hr = h1 + (size_t)idx*DM;
    #pragma unroll
    for (int d = 0; d < DM; ++d) hr[d] = acc[d] + xr[d];
}

// feat = relu(h_last @ fc_w + fc_b); logits = feat@cls_w+cls_b; mass = feat@reg_w+reg_b
__global__ __launch_bounds__(1024) void head_kernel(
    const float* __restrict__ ygT,   // layer-1 gated output (B,48,L)
    const float* __restrict__ fcw, const float* __restrict__ fcb,
    const float* __restrict__ clw, const float* __restrict__ clb,
    const float* __restrict__ rgw, const float* __restrict__ rgb,
    float* __restrict__ out)         // 80 floats: (16,4) logits then (16,) mass
{
    __shared__ float s_h[BB*48];
    __shared__ float s_f[BB*48];
    const int tid = threadIdx.x;
    const int b = tid >> 6, j = tid & 63;
    if (j < 48) s_h[b*48+j] = ygT[((size_t)b*48 + j)*LL + (LL-1)];
    __syncthreads();
    if (j < 48) {
        float acc = fcb[j];
        for (int k = 0; k < 48; ++k) acc += s_h[b*48+k]*fcw[k*48+j];
        s_f[b*48+j] = fmaxf(acc, 0.f);
    }
    __syncthreads();
    if (j < NCLS) {
        float acc = clb[j];
        for (int k = 0; k < 48; ++k) acc += s_f[b*48+k]*clw[k*NCLS+j];
        out[b*NCLS + j] = acc;
    }
    if (j == NCLS) {
        float acc = rgb[0];
        for (int k = 0; k < 48; ++k) acc += s_f[b*48+k]*rgw[k];
        out[BB*NCLS + b] = acc;
    }
}

extern "C" void kernel_launch(void* const* d_in, const int* in_sizes, int n_in,
                              void* d_out, int out_size, void* d_ws, size_t ws_size,
                              hipStream_t stream)
{
    const float* x     = (const float*)d_in[0];
    const float* ipw   = (const float*)d_in[1];   // (2,6,96)
    const float* cw    = (const float*)d_in[2];   // (2,48,16)
    const float* cb    = (const float*)d_in[3];   // (2,48)
    const float* xpw   = (const float*)d_in[4];   // (2,48,65)
    const float* dtw   = (const float*)d_in[5];   // (2,1,48)
    const float* dtb   = (const float*)d_in[6];   // (2,48)
    const float* A_log = (const float*)d_in[7];   // (2,48,32)
    const float* Dw    = (const float*)d_in[8];   // (2,48)
    const float* nw    = (const float*)d_in[9];   // (2,6)
    const float* opw   = (const float*)d_in[10];  // (1,48,6)
    const float* fcw   = (const float*)d_in[11];
    const float* fcb   = (const float*)d_in[12];
    const float* clw   = (const float*)d_in[13];
    const float* clb   = (const float*)d_in[14];
    const float* rgw   = (const float*)d_in[15];
    const float* rgb   = (const float*)d_in[16];
    float* out = (float*)d_out;

    float* ws = (float*)d_ws;
    const size_t BL = (size_t)BB*LL;
    const size_t SC = (size_t)BB*48*NC*32;
    float* xT  = ws;
    float* zT  = xT  + BL*48;
    float* dT  = zT  + BL*48;
    float* BT  = dT  + BL*48;
    float* CT  = BT  + BL*32;
    float* ygT = CT  + BL*32;
    float* h1  = ygT + BL*48;
    float* Pp  = h1  + BL*8;
    float* He  = Pp  + SC;
    float* Ca  = He  + SC;

    const dim3 scanGrid(BB*24*NC), scanBlk(64);

    // ---- layer 0 ----
    pre_kernel<<<dim3(BB*16), dim3(256), 0, stream>>>(
        x, ipw, nw, cw, cb, xpw, dtw, dtb, xT, zT, dT, BT, CT);
    scan1_kernel<<<scanGrid, scanBlk, 0, stream>>>(dT, xT, BT, A_log, Pp, He);
    scan2_kernel<<<dim3(BB*24), scanBlk, 0, stream>>>(Pp, He, Ca);
    scan3_kernel<<<scanGrid, scanBlk, 0, stream>>>(
        xT, zT, dT, BT, CT, A_log, Dw, Ca, ygT);
    proj0_kernel<<<dim3(BB*LL/256), dim3(256), 0, stream>>>(ygT, x, opw, h1);

    // ---- layer 1 ----
    pre_kernel<<<dim3(BB*16), dim3(256), 0, stream>>>(
        h1, ipw + 6*96, nw + 6, cw + 48*DCONVK, cb + 48,
        xpw + 48*65, dtw + 48, dtb + 48, xT, zT, dT, BT, CT);
    scan1_kernel<<<scanGrid, scanBlk, 0, stream>>>(
        dT, xT, BT, A_log + 48*NST, Pp, He);
    scan2_kernel<<<dim3(BB*24), scanBlk, 0, stream>>>(Pp, He, Ca);
    scan3_kernel<<<scanGrid, scanBlk, 0, stream>>>(
        xT, zT, dT, BT, CT, A_log + 48*NST, Dw + 48, Ca, ygT);

    head_kernel<<<dim3(1), dim3(1024), 0, stream>>>(
        ygT, fcw, fcb, clw, clb, rgw, rgb, out);
}

// Round 4
// 218.626 us; speedup vs baseline: 7.5746x; 1.2673x over previous
//
#include <hip/hip_runtime.h>
#include <math.h>

#define BB 16
#define LL 1024
#define DM 6
#define ED 48
#define NST 32
#define DCONVK 16
#define NCLS 4
#define CH 32    // positions per pre-kernel block
#define HALO 15
#define NCF 16   // scan chunks (= waves per scan block)
#define CSF 64   // chunk size = LL/NCF

__device__ __forceinline__ float softplus_f(float x) {
    return fmaxf(x, 0.f) + log1pf(expf(-fabsf(x)));
}
__device__ __forceinline__ float silu_f(float x) {
    return x / (1.f + __expf(-x));
}

// Fused: [MODE0: rmsnorm(x)] / [MODE1: ygT@opw + x residual -> rmsnorm]
//        -> in_proj -> split -> causal dwconv+silu -> x_proj -> softplus(delta)
// Outputs: xT/zT/dT transposed (B,48,L); Bi/Ci interleaved (B,L,32).
template<int MODE>
__global__ __launch_bounds__(256) void pre_kernel(
    const float* __restrict__ hin,     // x (B,L,6): MODE0 input / MODE1 residual
    const float* __restrict__ ygT_in,  // MODE1: (B,48,L)
    const float* __restrict__ opw,     // MODE1: (48,6)
    const float* __restrict__ ipw,     // (6,96)
    const float* __restrict__ nw,      // (6)
    const float* __restrict__ cw,      // (48,16)
    const float* __restrict__ cb,      // (48)
    const float* __restrict__ xpw,     // (48,65)
    const float* __restrict__ dtw,     // (48)
    const float* __restrict__ dtb,     // (48)
    float* __restrict__ xT,            // (B,48,L)
    float* __restrict__ zT,            // (B,48,L)
    float* __restrict__ dT,            // (B,48,L)
    float* __restrict__ Bi,            // (B,L,32)
    float* __restrict__ Ci)            // (B,L,32)
{
    __shared__ float s_ipw[6*96];
    __shared__ float s_nw[6];
    __shared__ float s_cw[48*DCONVK];
    __shared__ float s_cb[48];
    __shared__ float s_xpw[48*65];
    __shared__ float s_dtw[48];
    __shared__ float s_dtb[48];
    __shared__ float s_opw[48*6];
    __shared__ float s_pp[(CH+HALO)*4*6];
    __shared__ float s_u[(CH+HALO)*7];
    __shared__ float s_raw[(CH+HALO)*49];
    __shared__ float s_xsT[48*CH];        // [c][p] channel-major
    __shared__ float s_bc[64*33];         // [col][p] for B/C transpose-out
    __shared__ float s_dlt[CH];

    const int tid = threadIdx.x;
    const int b  = blockIdx.x >> 5;
    const int l0 = (blockIdx.x & 31) * CH;
    const int ROWS = CH + HALO;           // 47

    for (int i = tid; i < 6*96; i += 256) s_ipw[i] = ipw[i];
    if (tid < 6) s_nw[tid] = nw[tid];
    for (int i = tid; i < 48*DCONVK; i += 256) s_cw[i] = cw[i];
    if (tid < 48) s_cb[tid] = cb[tid];
    for (int i = tid; i < 48*65; i += 256) s_xpw[i] = xpw[i];
    if (tid < 48) { s_dtw[tid] = dtw[tid]; s_dtb[tid] = dtb[tid]; }
    if (MODE == 1) for (int i = tid; i < 48*6; i += 256) s_opw[i] = opw[i];
    __syncthreads();

    // ---- phase 0: produce s_u (normalized input rows l0-15 .. l0+CH-1) ----
    if (MODE == 0) {
        if (tid < ROWS) {
            int l = l0 - HALO + tid;
            float u[DM];
            if (l >= 0) {
                float ss = 0.f;
                const float* hp = hin + ((size_t)b*LL + l)*DM;
                #pragma unroll
                for (int d = 0; d < DM; ++d) { u[d] = hp[d]; ss += u[d]*u[d]; }
                float sc = rsqrtf(ss * (1.f/DM) + 1e-5f);
                #pragma unroll
                for (int d = 0; d < DM; ++d) u[d] *= sc * s_nw[d];
            } else {
                #pragma unroll
                for (int d = 0; d < DM; ++d) u[d] = 0.f;
            }
            #pragma unroll
            for (int d = 0; d < DM; ++d) s_u[tid*7+d] = u[d];
        }
        __syncthreads();
    } else {
        // proj0 fused: acc = ygT^T @ opw (split over 4 e-groups), + residual, rmsnorm
        const int g = tid >> 6, t = tid & 63;
        if (t < ROWS) {
            int l = l0 - HALO + t;
            float pacc[DM] = {0,0,0,0,0,0};
            if (l >= 0) {
                for (int e = g*12; e < g*12 + 12; ++e) {
                    float v = ygT_in[((size_t)b*48 + e)*LL + l];
                    #pragma unroll
                    for (int d = 0; d < DM; ++d) pacc[d] += v * s_opw[e*DM+d];
                }
            }
            #pragma unroll
            for (int d = 0; d < DM; ++d) s_pp[(t*4+g)*DM+d] = pacc[d];
        }
        __syncthreads();
        if (tid < ROWS) {
            int l = l0 - HALO + tid;
            float u[DM];
            if (l >= 0) {
                const float* xr = hin + ((size_t)b*LL + l)*DM;
                float ss = 0.f;
                #pragma unroll
                for (int d = 0; d < DM; ++d) {
                    float hv = s_pp[(tid*4+0)*DM+d] + s_pp[(tid*4+1)*DM+d]
                             + s_pp[(tid*4+2)*DM+d] + s_pp[(tid*4+3)*DM+d] + xr[d];
                    u[d] = hv; ss += hv*hv;
                }
                float sc = rsqrtf(ss * (1.f/DM) + 1e-5f);
                #pragma unroll
                for (int d = 0; d < DM; ++d) u[d] *= sc * s_nw[d];
            } else {
                #pragma unroll
                for (int d = 0; d < DM; ++d) u[d] = 0.f;
            }
            #pragma unroll
            for (int d = 0; d < DM; ++d) s_u[tid*7+d] = u[d];
        }
        __syncthreads();
    }

    // ---- phase 1: in_proj (96 cols x ROWS rows) ----
    for (int i = tid; i < 96*ROWS; i += 256) {
        int j = i / ROWS, t = i - j*ROWS;
        float acc = 0.f;
        #pragma unroll
        for (int d = 0; d < DM; ++d) acc += s_u[t*7+d]*s_ipw[d*96+j];
        if (j < 48) s_raw[t*49+j] = acc;
        else if (t >= HALO) zT[((size_t)b*48 + (j-48))*LL + (l0 - HALO + t)] = acc;
    }
    __syncthreads();

    // ---- phase 2: depthwise causal conv (K=16) + silu ----
    for (int o = tid; o < 48*CH; o += 256) {
        int c = o >> 5, p = o & 31;
        float acc = s_cb[c];
        #pragma unroll
        for (int k = 0; k < DCONVK; ++k)
            acc += s_raw[(p+k)*49 + c] * s_cw[c*DCONVK + k];
        float v = silu_f(acc);
        s_xsT[c*CH + p] = v;
        xT[((size_t)b*48 + c)*LL + l0 + p] = v;
    }
    __syncthreads();

    // ---- phase 3: x_proj, vectorized 4 positions per lane ----
    // item = j*8 + g : col j in [0,65), p-group g in [0,8)
    for (int i = tid; i < 65*8; i += 256) {
        int j = i >> 3, g = i & 7;
        int col = (j == 64) ? 0 : (j + 1);
        float a0=0.f, a1=0.f, a2=0.f, a3=0.f;
        for (int e = 0; e < 48; ++e) {
            float4 xv = *(const float4*)&s_xsT[e*CH + 4*g];
            float w = s_xpw[e*65 + col];
            a0 = fmaf(xv.x, w, a0); a1 = fmaf(xv.y, w, a1);
            a2 = fmaf(xv.z, w, a2); a3 = fmaf(xv.w, w, a3);
        }
        if (j < 64) {
            s_bc[j*33 + 4*g+0] = a0; s_bc[j*33 + 4*g+1] = a1;
            s_bc[j*33 + 4*g+2] = a2; s_bc[j*33 + 4*g+3] = a3;
        } else {
            s_dlt[4*g+0] = a0; s_dlt[4*g+1] = a1;
            s_dlt[4*g+2] = a2; s_dlt[4*g+3] = a3;
        }
    }
    __syncthreads();

    // ---- phase 3b: write B/C interleaved (coalesced) ----
    for (int o = tid; o < 2*CH*32; o += 256) {
        int which = o >> 10;            // 0:B 1:C
        int l = (o >> 5) & (CH-1), n = o & 31;
        float v = s_bc[(which*32 + n)*33 + l];
        float* dst = which ? Ci : Bi;
        dst[((size_t)b*LL + l0 + l)*32 + n] = v;
    }

    // ---- phase 4: delta = softplus(dlt*dt_w + dt_b), transposed write ----
    for (int o = tid; o < 48*CH; o += 256) {
        int e = o >> 5, p = o & 31;
        float xv = s_dlt[p]*s_dtw[e] + s_dtb[e];
        dT[((size_t)b*48 + e)*LL + l0 + p] = softplus_f(xv);
    }
}

// ---- fully fused selective scan: local scan + carry + rescan + gate ----
// Block = (b, epair). 1024 threads = 16 waves; wave w owns chunk w (64 steps).
// Wave lane = eh*32 + n (eh: which of 2 e-channels, n: state index).
__global__ __launch_bounds__(1024) void scan_fused(
    const float* __restrict__ dT,
    const float* __restrict__ xT,
    const float* __restrict__ zT,
    const float* __restrict__ Bi,
    const float* __restrict__ Ci,
    const float* __restrict__ A_log,  // (48,32)
    const float* __restrict__ Dw,     // (48)
    float* __restrict__ ygT)          // (B,48,L)
{
    __shared__ float2 sPH[2][NCF][32];
    __shared__ float  sCa[2][NCF][32];

    const int tid = threadIdx.x;
    const int c = tid >> 6;           // wave = chunk
    const int lane = tid & 63;
    const int eh = lane >> 5, n = lane & 31;
    const int b = blockIdx.x / 24;
    const int epair = blockIdx.x % 24;
    const int e = epair*2 + eh;

    const float Ac = -__expf(A_log[e*NST + n]);
    const float Dc = Dw[e];

    const size_t eb = ((size_t)b*48 + e)*LL + c*CSF;
    const float4* dp = (const float4*)(dT + eb);
    const float4* xp = (const float4*)(xT + eb);
    const float*  bp = Bi + ((size_t)b*LL + c*CSF)*32 + n;

    // phase A: local scan (h0 = 0), P via exp(Ac * sum(delta))
    float h = 0.f, S = 0.f;
    #pragma unroll 4
    for (int q = 0; q < CSF/4; ++q) {
        float4 d4 = dp[q], x4 = xp[q];
        float b0 = bp[(4*q+0)*32], b1 = bp[(4*q+1)*32];
        float b2 = bp[(4*q+2)*32], b3 = bp[(4*q+3)*32];
        S += d4.x + d4.y + d4.z + d4.w;
        h = fmaf(__expf(d4.x*Ac), h, d4.x*x4.x*b0);
        h = fmaf(__expf(d4.y*Ac), h, d4.y*x4.y*b1);
        h = fmaf(__expf(d4.z*Ac), h, d4.z*x4.z*b2);
        h = fmaf(__expf(d4.w*Ac), h, d4.w*x4.w*b3);
    }
    sPH[eh][c][n] = make_float2(__expf(Ac*S), h);
    __syncthreads();

    // phase B: carry scan over chunks (wave 0; reg-preloaded so loads pipeline)
    if (tid < 64) {
        float2 v[NCF];
        #pragma unroll
        for (int k = 0; k < NCF; ++k) v[k] = sPH[eh][k][n];
        float acc = 0.f;
        #pragma unroll
        for (int k = 0; k < NCF; ++k) {
            sCa[eh][k][n] = acc;
            acc = fmaf(v[k].x, acc, v[k].y);
        }
    }
    __syncthreads();

    // phase C: rescan with carry; fused y-reduce + D*x + silu(z) gate
    h = sCa[eh][c][n];
    const float*  cp = Ci + ((size_t)b*LL + c*CSF)*32 + n;
    const float4* zp = (const float4*)(zT + eb);
    float4* yp = (float4*)(ygT + eb);

    #pragma unroll 4
    for (int q = 0; q < CSF/4; ++q) {
        float4 d4 = dp[q], x4 = xp[q];
        float b0 = bp[(4*q+0)*32], b1 = bp[(4*q+1)*32];
        float b2 = bp[(4*q+2)*32], b3 = bp[(4*q+3)*32];
        float c0 = cp[(4*q+0)*32], c1 = cp[(4*q+1)*32];
        float c2 = cp[(4*q+2)*32], c3 = cp[(4*q+3)*32];
        float p0, p1, p2, p3;
        h = fmaf(__expf(d4.x*Ac), h, d4.x*x4.x*b0); p0 = h*c0;
        h = fmaf(__expf(d4.y*Ac), h, d4.y*x4.y*b1); p1 = h*c1;
        h = fmaf(__expf(d4.z*Ac), h, d4.z*x4.z*b2); p2 = h*c2;
        h = fmaf(__expf(d4.w*Ac), h, d4.w*x4.w*b3); p3 = h*c3;
        // packed butterfly reduce over 32 n-lanes (within eh half)
        float q0 = p0 + __shfl_xor(p0, 16);
        float q1 = p1 + __shfl_xor(p1, 16);
        float q2 = p2 + __shfl_xor(p2, 16);
        float q3 = p3 + __shfl_xor(p3, 16);
        float m01 = (n & 16) ? q1 : q0;
        float m23 = (n & 16) ? q3 : q2;
        m01 += __shfl_xor(m01, 8); m23 += __shfl_xor(m23, 8);
        m01 += __shfl_xor(m01, 4); m23 += __shfl_xor(m23, 4);
        m01 += __shfl_xor(m01, 2); m23 += __shfl_xor(m23, 2);
        m01 += __shfl_xor(m01, 1); m23 += __shfl_xor(m23, 1);
        float y1 = __shfl_xor(m01, 16);
        float y3 = __shfl_xor(m23, 16);
        if (n == 0) {
            float4 z4 = zp[q];
            float4 y;
            y.x = (m01 + Dc*x4.x) * silu_f(z4.x);
            y.y = (y1  + Dc*x4.y) * silu_f(z4.y);
            y.z = (m23 + Dc*x4.z) * silu_f(z4.z);
            y.w = (y3  + Dc*x4.w) * silu_f(z4.w);
            yp[q] = y;
        }
    }
}

// feat = relu(h_last @ fc_w + fc_b); logits = feat@cls_w+cls_b; mass = feat@reg_w+reg_b
__global__ __launch_bounds__(1024) void head_kernel(
    const float* __restrict__ ygT,   // layer-1 gated output (B,48,L)
    const float* __restrict__ fcw, const float* __restrict__ fcb,
    const float* __restrict__ clw, const float* __restrict__ clb,
    const float* __restrict__ rgw, const float* __restrict__ rgb,
    float* __restrict__ out)         // 80 floats: (16,4) logits then (16,) mass
{
    __shared__ float s_h[BB*48];
    __shared__ float s_f[BB*48];
    const int tid = threadIdx.x;
    const int b = tid >> 6, j = tid & 63;
    if (j < 48) s_h[b*48+j] = ygT[((size_t)b*48 + j)*LL + (LL-1)];
    __syncthreads();
    if (j < 48) {
        float acc = fcb[j];
        for (int k = 0; k < 48; ++k) acc += s_h[b*48+k]*fcw[k*48+j];
        s_f[b*48+j] = fmaxf(acc, 0.f);
    }
    __syncthreads();
    if (j < NCLS) {
        float acc = clb[j];
        for (int k = 0; k < 48; ++k) acc += s_f[b*48+k]*clw[k*NCLS+j];
        out[b*NCLS + j] = acc;
    }
    if (j == NCLS) {
        float acc = rgb[0];
        for (int k = 0; k < 48; ++k) acc += s_f[b*48+k]*rgw[k];
        out[BB*NCLS + b] = acc;
    }
}

extern "C" void kernel_launch(void* const* d_in, const int* in_sizes, int n_in,
                              void* d_out, int out_size, void* d_ws, size_t ws_size,
                              hipStream_t stream)
{
    const float* x     = (const float*)d_in[0];
    const float* ipw   = (const float*)d_in[1];   // (2,6,96)
    const float* cw    = (const float*)d_in[2];   // (2,48,16)
    const float* cb    = (const float*)d_in[3];   // (2,48)
    const float* xpw   = (const float*)d_in[4];   // (2,48,65)
    const float* dtw   = (const float*)d_in[5];   // (2,1,48)
    const float* dtb   = (const float*)d_in[6];   // (2,48)
    const float* A_log = (const float*)d_in[7];   // (2,48,32)
    const float* Dw    = (const float*)d_in[8];   // (2,48)
    const float* nw    = (const float*)d_in[9];   // (2,6)
    const float* opw   = (const float*)d_in[10];  // (1,48,6)
    const float* fcw   = (const float*)d_in[11];
    const float* fcb   = (const float*)d_in[12];
    const float* clw   = (const float*)d_in[13];
    const float* clb   = (const float*)d_in[14];
    const float* rgw   = (const float*)d_in[15];
    const float* rgb   = (const float*)d_in[16];
    float* out = (float*)d_out;

    float* ws = (float*)d_ws;
    const size_t BL = (size_t)BB*LL;
    float* xT  = ws;
    float* zT  = xT  + BL*48;
    float* dT  = zT  + BL*48;
    float* Bi  = dT  + BL*48;
    float* Ci  = Bi  + BL*32;
    float* ygT = Ci  + BL*32;

    const dim3 preGrid(BB*32), preBlk(256);
    const dim3 scanGrid(BB*24), scanBlk(1024);

    // ---- layer 0 ----
    pre_kernel<0><<<preGrid, preBlk, 0, stream>>>(
        x, nullptr, nullptr, ipw, nw, cw, cb, xpw, dtw, dtb,
        xT, zT, dT, Bi, Ci);
    scan_fused<<<scanGrid, scanBlk, 0, stream>>>(
        dT, xT, zT, Bi, Ci, A_log, Dw, ygT);

    // ---- layer 1 (proj0 + residual + rmsnorm fused into pre) ----
    pre_kernel<1><<<preGrid, preBlk, 0, stream>>>(
        x, ygT, opw, ipw + 6*96, nw + 6, cw + 48*DCONVK, cb + 48,
        xpw + 48*65, dtw + 48, dtb + 48,
        xT, zT, dT, Bi, Ci);
    scan_fused<<<scanGrid, scanBlk, 0, stream>>>(
        dT, xT, zT, Bi, Ci, A_log + 48*NST, Dw + 48, ygT);

    head_kernel<<<dim3(1), dim3(1024), 0, stream>>>(
        ygT, fcw, fcb, clw, clb, rgw, rgb, out);
}